// Round 4
// baseline (280.114 us; speedup 1.0000x reference)
//
#include <hip/hip_runtime.h>

#define NCLASS 5
#define NB 2
#define VOX (96*160*160)   // 2,457,600 voxels per batch item
#define V4  (VOX/4)        // 614,400 float4 packs per batch item
#define SLOTS 64           // atomic shards
#define VALS  110          // 50 S + 50 T + 10 cnt
#define STAGP 1271         // per-class pack stagger (breaks channel-phase alignment)

// ws layout: float ws[SLOTS][VALS]; within a slot:
//   [0,50)    : S sums   idx = (b*5 + k)*5 + c
//   [50,100)  : T sums   idx = 50 + (b*5 + k)*5 + c
//   [100,110) : counts   idx = 100 + b*5 + k

__global__ __launch_bounds__(256)
void kd_partial(const float* __restrict__ src, const float* __restrict__ tgt,
                const int* __restrict__ gt, float* __restrict__ ws)
{
    const int nbPerB = gridDim.x >> 1;           // blocks per batch item
    const int b      = blockIdx.x / nbPerB;      // 0 or 1
    const int blk    = blockIdx.x - b * nbPerB;

    const float* sb = src + (size_t)b * NCLASS * VOX;
    const float* tb = tgt + (size_t)b * NCLASS * VOX;
    const int*   gb = gt  + (size_t)b * VOX;

    float accS[NCLASS][NCLASS];
    float accT[NCLASS][NCLASS];
    float cnt[NCLASS];
    #pragma unroll
    for (int k = 0; k < NCLASS; ++k) {
        cnt[k] = 0.f;
        #pragma unroll
        for (int c = 0; c < NCLASS; ++c) { accS[k][c] = 0.f; accT[k][c] = 0.f; }
    }

    const int tid    = blk * 256 + threadIdx.x;
    const int stride = nbPerB * 256;

    for (int i = tid; i < V4; i += stride) {
        #pragma unroll
        for (int c = 0; c < NCLASS; ++c) {
            // staggered pack index for this class (each stream still read exactly once)
            int ic = i + c * STAGP;
            if (ic >= V4) ic -= V4;
            const int4   g4 = ((const int4*)gb)[ic];
            const float4 s4 = ((const float4*)(sb + (size_t)c * VOX))[ic];
            const float4 t4 = ((const float4*)(tb + (size_t)c * VOX))[ic];

            #define ACC_COMP(GX, SX, TX)                                     \
                { _Pragma("unroll")                                          \
                  for (int kk = 0; kk < NCLASS; ++kk) {                      \
                      const float m = ((GX) == kk) ? 1.0f : 0.0f;            \
                      accS[kk][c] = fmaf(m, (SX), accS[kk][c]);              \
                      accT[kk][c] = fmaf(m, (TX), accT[kk][c]);              \
                  } }
            ACC_COMP(g4.x, s4.x, t4.x)
            ACC_COMP(g4.y, s4.y, t4.y)
            ACC_COMP(g4.z, s4.z, t4.z)
            ACC_COMP(g4.w, s4.w, t4.w)
            #undef ACC_COMP

            if (c == 0) {   // count each voxel exactly once (unstaggered pass)
                #pragma unroll
                for (int kk = 0; kk < NCLASS; ++kk) {
                    cnt[kk] += ((g4.x == kk) ? 1.f : 0.f) + ((g4.y == kk) ? 1.f : 0.f)
                             + ((g4.z == kk) ? 1.f : 0.f) + ((g4.w == kk) ? 1.f : 0.f);
                }
            }
        }
    }

    // ---- block-level reduction: wave shuffle -> LDS -> sharded global atomic ----
    __shared__ float lacc[55];
    const int lane = threadIdx.x & 63;
    if (threadIdx.x < 55) lacc[threadIdx.x] = 0.f;
    __syncthreads();

    #define WAVE_RED(VAL, IDX) {                                             \
        float v_ = (VAL);                                                    \
        _Pragma("unroll")                                                    \
        for (int off_ = 32; off_; off_ >>= 1) v_ += __shfl_xor(v_, off_);    \
        if (lane == 0) atomicAdd(&lacc[(IDX)], v_);                          \
    }
    #pragma unroll
    for (int k = 0; k < NCLASS; ++k) {
        #pragma unroll
        for (int c = 0; c < NCLASS; ++c) {
            WAVE_RED(accS[k][c], k * 5 + c);
            WAVE_RED(accT[k][c], 25 + k * 5 + c);
        }
        WAVE_RED(cnt[k], 50 + k);
    }
    #undef WAVE_RED
    __syncthreads();

    if (threadIdx.x < 55) {
        const int i = threadIdx.x;
        int gidx;
        if (i < 25)       gidx = b * 25 + i;                 // S
        else if (i < 50)  gidx = 50 + b * 25 + (i - 25);     // T
        else              gidx = 100 + b * 5 + (i - 50);     // counts
        atomicAdd(&ws[(blockIdx.x & (SLOTS - 1)) * VALS + gidx], lacc[i]);
    }
}

__global__ void kd_final(const float* __restrict__ ws, float* __restrict__ out)
{
    const int tid = threadIdx.x;   // one wave of 64
    __shared__ float tot[VALS];

    // cooperative slot-sum: tot[v] = sum over 64 shards
    for (int v = tid; v < VALS; v += 64) {
        float s = 0.f;
        #pragma unroll 8
        for (int slot = 0; slot < SLOTS; ++slot) s += ws[slot * VALS + v];
        tot[v] = s;
    }
    __syncthreads();

    // 40 lanes: one (k,b,c) term each; 4-lane groups share a softmax row
    const int l = (tid < 40) ? tid : 0;
    const int g = l >> 2;          // 0..9
    const int k = g >> 1;          // 0..4
    const int b = g & 1;           // 0..1
    const int c = l & 3;           // 0..3  (class c+1)

    const double denom = (double)tot[100 + 0 * 5 + k]
                       + (double)tot[100 + 1 * 5 + k] + 1e-6;
    double sa = ((double)tot[(b * 5 + k) * 5 + (c + 1)] / denom) * 0.5;
    double ta = ((double)tot[50 + (b * 5 + k) * 5 + (c + 1)] / denom) * 0.5;

    // group max (4-lane aligned groups: xor 1,2 stay inside)
    double ms = sa, mt = ta;
    ms = fmax(ms, __shfl_xor(ms, 1)); ms = fmax(ms, __shfl_xor(ms, 2));
    mt = fmax(mt, __shfl_xor(mt, 1)); mt = fmax(mt, __shfl_xor(mt, 2));
    double es = exp(sa - ms), et = exp(ta - mt);
    es += __shfl_xor(es, 1); es += __shfl_xor(es, 2);
    et += __shfl_xor(et, 1); et += __shfl_xor(et, 2);
    const double slp = sa - (ms + log(es));
    const double tlp = ta - (mt + log(et));

    double term = exp(tlp) * (tlp - slp) + exp(slp) * (slp - tlp);
    if (tid >= 40) term = 0.0;

    #pragma unroll
    for (int off = 32; off; off >>= 1) term += __shfl_xor(term, off);
    if (tid == 0) out[0] = (float)(term / 20.0);
}

extern "C" void kernel_launch(void* const* d_in, const int* in_sizes, int n_in,
                              void* d_out, int out_size, void* d_ws, size_t ws_size,
                              hipStream_t stream)
{
    const float* src = (const float*)d_in[0];
    const float* tgt = (const float*)d_in[1];
    const int*   gt  = (const int*)d_in[2];
    float* out = (float*)d_out;
    float* ws  = (float*)d_ws;

    hipMemsetAsync(ws, 0, SLOTS * VALS * sizeof(float), stream);
    kd_partial<<<dim3(2048), dim3(256), 0, stream>>>(src, tgt, gt, ws);
    kd_final<<<dim3(1), dim3(64), 0, stream>>>(ws, out);
}

// Round 7
// 237.622 us; speedup vs baseline: 1.1788x; 1.1788x over previous
//
#include <hip/hip_runtime.h>

#define NCLASS 5
#define NB 2
#define VOX (96*160*160)   // 2,457,600 voxels per batch item
#define V4  (VOX/4)        // 614,400 float4 packs per batch item
#define SLOTS 64           // atomic shards
#define VALS  110          // 50 S + 50 T + 10 cnt
#define BLKS_PER_SLAB 256

// ws layout: float ws[SLOTS][VALS]; within a slot:
//   [0,50)    : S sums   idx = (b*5 + k)*5 + c
//   [50,100)  : T sums   idx = 50 + (b*5 + k)*5 + c
//   [100,110) : counts   idx = 100 + b*5 + k

__global__ __launch_bounds__(256)
void kd_partial(const float* __restrict__ src, const float* __restrict__ tgt,
                const int* __restrict__ gt, float* __restrict__ ws)
{
    // One (b,c) slab per blockIdx.y: 3 contiguous streams per block (copy shape).
    const int b = blockIdx.y / NCLASS;   // 0..1
    const int c = blockIdx.y % NCLASS;   // 0..4  (block-uniform!)

    const float* sb = src + ((size_t)b * NCLASS + c) * VOX;
    const float* tb = tgt + ((size_t)b * NCLASS + c) * VOX;
    const int*   gb = gt  + (size_t)b * VOX;

    float accS[NCLASS] = {0.f, 0.f, 0.f, 0.f, 0.f};
    float accT[NCLASS] = {0.f, 0.f, 0.f, 0.f, 0.f};
    float cnt[NCLASS]  = {0.f, 0.f, 0.f, 0.f, 0.f};

    const int tid    = blockIdx.x * 256 + threadIdx.x;
    const int stride = BLKS_PER_SLAB * 256;

    #define BODY(WITH_CNT)                                                    \
        for (int i = tid; i < V4; i += stride) {                              \
            const int4   g4 = ((const int4*)gb)[i];                           \
            const float4 s4 = ((const float4*)sb)[i];                         \
            const float4 t4 = ((const float4*)tb)[i];                         \
            _Pragma("unroll")                                                 \
            for (int kk = 0; kk < NCLASS; ++kk) {                             \
                const float mx = (g4.x == kk) ? 1.f : 0.f;                    \
                const float my = (g4.y == kk) ? 1.f : 0.f;                    \
                const float mz = (g4.z == kk) ? 1.f : 0.f;                    \
                const float mw = (g4.w == kk) ? 1.f : 0.f;                    \
                accS[kk] = fmaf(mx, s4.x, accS[kk]);                          \
                accS[kk] = fmaf(my, s4.y, accS[kk]);                          \
                accS[kk] = fmaf(mz, s4.z, accS[kk]);                          \
                accS[kk] = fmaf(mw, s4.w, accS[kk]);                          \
                accT[kk] = fmaf(mx, t4.x, accT[kk]);                          \
                accT[kk] = fmaf(my, t4.y, accT[kk]);                          \
                accT[kk] = fmaf(mz, t4.z, accT[kk]);                          \
                accT[kk] = fmaf(mw, t4.w, accT[kk]);                          \
                if (WITH_CNT) cnt[kk] += mx + my + mz + mw;                   \
            }                                                                 \
        }
    if (c == 0) { BODY(1) } else { BODY(0) }
    #undef BODY

    // ---- block reduction: wave shuffle -> LDS -> sharded global atomic ----
    __shared__ float lacc[15];   // 0..4 S, 5..9 T, 10..14 cnt
    const int lane = threadIdx.x & 63;
    if (threadIdx.x < 15) lacc[threadIdx.x] = 0.f;
    __syncthreads();

    #define WAVE_RED(VAL, IDX) {                                              \
        float v_ = (VAL);                                                     \
        _Pragma("unroll")                                                     \
        for (int off_ = 32; off_; off_ >>= 1) v_ += __shfl_xor(v_, off_);     \
        if (lane == 0) atomicAdd(&lacc[(IDX)], v_);                           \
    }
    #pragma unroll
    for (int kk = 0; kk < NCLASS; ++kk) {
        WAVE_RED(accS[kk], kk);
        WAVE_RED(accT[kk], 5 + kk);
    }
    if (c == 0) {
        #pragma unroll
        for (int kk = 0; kk < NCLASS; ++kk) WAVE_RED(cnt[kk], 10 + kk);
    }
    #undef WAVE_RED
    __syncthreads();

    const int slot = (blockIdx.x + blockIdx.y * 37) & (SLOTS - 1);
    if (threadIdx.x < 15) {
        const int i  = threadIdx.x;
        const int kk = i % 5;
        int gidx = -1;
        if (i < 5)        gidx = (b * 5 + kk) * 5 + c;        // S
        else if (i < 10)  gidx = 50 + (b * 5 + kk) * 5 + c;   // T
        else if (c == 0)  gidx = 100 + b * 5 + kk;            // cnt (c==0 blocks only)
        if (gidx >= 0) atomicAdd(&ws[slot * VALS + gidx], lacc[i]);
    }
}

__global__ void kd_final(const float* __restrict__ ws, float* __restrict__ out)
{
    const int tid = threadIdx.x;   // one wave of 64
    __shared__ float tot[VALS];

    // cooperative slot-sum: tot[v] = sum over 64 shards
    for (int v = tid; v < VALS; v += 64) {
        float s = 0.f;
        #pragma unroll 8
        for (int slot = 0; slot < SLOTS; ++slot) s += ws[slot * VALS + v];
        tot[v] = s;
    }
    __syncthreads();

    // 40 lanes: one (k,b,c) term each; 4-lane groups share a softmax row
    const int l = (tid < 40) ? tid : 0;
    const int g = l >> 2;          // 0..9
    const int k = g >> 1;          // 0..4
    const int b = g & 1;           // 0..1
    const int c = l & 3;           // 0..3  (class c+1)

    const double denom = (double)tot[100 + 0 * 5 + k]
                       + (double)tot[100 + 1 * 5 + k] + 1e-6;
    double sa = ((double)tot[(b * 5 + k) * 5 + (c + 1)] / denom) * 0.5;
    double ta = ((double)tot[50 + (b * 5 + k) * 5 + (c + 1)] / denom) * 0.5;

    // group max (4-lane aligned groups: xor 1,2 stay inside)
    double ms = sa, mt = ta;
    ms = fmax(ms, __shfl_xor(ms, 1)); ms = fmax(ms, __shfl_xor(ms, 2));
    mt = fmax(mt, __shfl_xor(mt, 1)); mt = fmax(mt, __shfl_xor(mt, 2));
    double es = exp(sa - ms), et = exp(ta - mt);
    es += __shfl_xor(es, 1); es += __shfl_xor(es, 2);
    et += __shfl_xor(et, 1); et += __shfl_xor(et, 2);
    const double slp = sa - (ms + log(es));
    const double tlp = ta - (mt + log(et));

    double term = exp(tlp) * (tlp - slp) + exp(slp) * (slp - tlp);
    if (tid >= 40) term = 0.0;

    #pragma unroll
    for (int off = 32; off; off >>= 1) term += __shfl_xor(term, off);
    if (tid == 0) out[0] = (float)(term / 20.0);
}

extern "C" void kernel_launch(void* const* d_in, const int* in_sizes, int n_in,
                              void* d_out, int out_size, void* d_ws, size_t ws_size,
                              hipStream_t stream)
{
    const float* src = (const float*)d_in[0];
    const float* tgt = (const float*)d_in[1];
    const int*   gt  = (const int*)d_in[2];
    float* out = (float*)d_out;
    float* ws  = (float*)d_ws;

    hipMemsetAsync(ws, 0, SLOTS * VALS * sizeof(float), stream);
    kd_partial<<<dim3(BLKS_PER_SLAB, NB * NCLASS), dim3(256), 0, stream>>>(src, tgt, gt, ws);
    kd_final<<<dim3(1), dim3(64), 0, stream>>>(ws, out);
}